// Round 1
// baseline (166.596 us; speedup 1.0000x reference)
//
#include <hip/hip_runtime.h>

// Chamfer distance, B=8, N=M=8192, fp32.
// d(i,j) = sq1_i + sq2_j - 2*inner  (matches reference formula exactly)
// min_j d = sq1_i + min_j (sq2_j - 2*inner_j)   -> 5 VALU ops per pair.

#define B_   8
#define N_   8192      // points per batch in xyz1 (== M_ for xyz2)
#define M_   8192
#define SPLIT 8        // j-range split for occupancy (4 waves/SIMD)
#define BLK  256
#define BN   (B_ * N_) // 65536 total owner points per direction
#define CH   (M_ / SPLIT)

// Pack [B*N][3] f32 -> [B*N] float4 (x, y, z, x^2+y^2+z^2)
__global__ void pack_kernel(const float* __restrict__ xyz,
                            float4* __restrict__ p, int total) {
    int i = blockIdx.x * blockDim.x + threadIdx.x;
    if (i < total) {
        float x = xyz[3 * i + 0];
        float y = xyz[3 * i + 1];
        float z = xyz[3 * i + 2];
        p[i] = make_float4(x, y, z, fmaf(x, x, fmaf(y, y, z * z)));
    }
}

// Each block: 256 threads, one batch, 512 owner points (2 per thread).
// gridDim.x = B_ * (N_/2/BLK) = 8*16 = 128 ; gridDim.y = SPLIT.
// Batch index derived from blockIdx only -> Q[j] address is wave-uniform
// -> scalar (s_load) path; inner loop is pure VALU.
__global__ __launch_bounds__(BLK)
void cham_min_kernel(const float4* __restrict__ P,   // owner packed [BN]
                     const float4* __restrict__ Q,   // other packed [BN]
                     float* __restrict__ partial) {  // [SPLIT][BN]
    const int blocksPerBatch = (N_ / 2) / BLK;       // 16
    const int b = blockIdx.x / blocksPerBatch;
    const int r = (blockIdx.x % blocksPerBatch) * BLK + threadIdx.x;
    const int i0 = b * N_ + r;
    const int i1 = i0 + N_ / 2;
    const int s = blockIdx.y;

    const float4* __restrict__ q = Q + (size_t)b * M_ + (size_t)s * CH;

    const float4 A0 = P[i0];
    const float4 A1 = P[i1];

    float m0a = 3.0e38f, m0b = 3.0e38f;
    float m1a = 3.0e38f, m1b = 3.0e38f;

#pragma unroll 8
    for (int j = 0; j < CH; j += 2) {
        float4 q0 = q[j];
        float4 q1 = q[j + 1];
        float t00 = fmaf(A0.x, q0.x, fmaf(A0.y, q0.y, A0.z * q0.z));
        float t01 = fmaf(A0.x, q1.x, fmaf(A0.y, q1.y, A0.z * q1.z));
        float t10 = fmaf(A1.x, q0.x, fmaf(A1.y, q0.y, A1.z * q0.z));
        float t11 = fmaf(A1.x, q1.x, fmaf(A1.y, q1.y, A1.z * q1.z));
        m0a = fminf(m0a, fmaf(-2.0f, t00, q0.w));
        m0b = fminf(m0b, fmaf(-2.0f, t01, q1.w));
        m1a = fminf(m1a, fmaf(-2.0f, t10, q0.w));
        m1b = fminf(m1b, fmaf(-2.0f, t11, q1.w));
    }

    partial[(size_t)s * BN + i0] = fminf(m0a, m0b);
    partial[(size_t)s * BN + i1] = fminf(m1a, m1b);
}

// min over SPLIT partials, add owner sq, write final distances.
__global__ void reduce_kernel(const float* __restrict__ partial,
                              const float4* __restrict__ P,
                              float* __restrict__ out, int total) {
    int i = blockIdx.x * blockDim.x + threadIdx.x;
    if (i < total) {
        float m = partial[i];
#pragma unroll
        for (int s = 1; s < SPLIT; ++s)
            m = fminf(m, partial[(size_t)s * total + i]);
        out[i] = m + P[i].w;
    }
}

extern "C" void kernel_launch(void* const* d_in, const int* in_sizes, int n_in,
                              void* d_out, int out_size, void* d_ws, size_t ws_size,
                              hipStream_t stream) {
    const float* xyz1 = (const float*)d_in[0];
    const float* xyz2 = (const float*)d_in[1];
    float* out = (float*)d_out;

    // workspace layout: p1 (1MB) | p2 (1MB) | part1 (2MB) | part2 (2MB)
    float4* p1 = (float4*)d_ws;
    float4* p2 = p1 + BN;
    float* part1 = (float*)(p2 + BN);
    float* part2 = part1 + (size_t)SPLIT * BN;

    pack_kernel<<<(BN + BLK - 1) / BLK, BLK, 0, stream>>>(xyz1, p1, BN);
    pack_kernel<<<(BN + BLK - 1) / BLK, BLK, 0, stream>>>(xyz2, p2, BN);

    dim3 grid(B_ * (N_ / 2 / BLK), SPLIT);
    // dist1: owners = xyz1 points, sweep xyz2
    cham_min_kernel<<<grid, BLK, 0, stream>>>(p1, p2, part1);
    // dist2: owners = xyz2 points, sweep xyz1 (shapes symmetric)
    cham_min_kernel<<<grid, BLK, 0, stream>>>(p2, p1, part2);

    reduce_kernel<<<(BN + BLK - 1) / BLK, BLK, 0, stream>>>(part1, p1, out, BN);
    reduce_kernel<<<(BN + BLK - 1) / BLK, BLK, 0, stream>>>(part2, p2, out + BN, BN);
}

// Round 2
// 140.161 us; speedup vs baseline: 1.1886x; 1.1886x over previous
//
#include <hip/hip_runtime.h>

// Chamfer distance, B=8, N=M=8192, fp32.
// Swept points pre-packed as q' = (-2x, -2y, -2z, x^2+y^2+z^2) so
//   d(i,j) - sq_i = fma(Ax,q'x, fma(Ay,q'y, fma(Az,q'z, q'w)))  -> 3 fma + min per pair.
// Owner sq_i added in the reduce. Both directions in ONE main dispatch (gridDim.z).

#define B_    8
#define N_    8192
#define M_    8192
#define SPLIT 8
#define BLK   256
#define BN    (B_ * N_)     // 65536
#define CH    (M_ / SPLIT)  // 1024

// Pack [total][3] f32 -> [total] float4 (-2x, -2y, -2z, x^2+y^2+z^2)
__global__ void pack_kernel(const float* __restrict__ xyz,
                            float4* __restrict__ p, int total) {
    int i = blockIdx.x * blockDim.x + threadIdx.x;
    if (i < total) {
        float x = xyz[3 * i + 0];
        float y = xyz[3 * i + 1];
        float z = xyz[3 * i + 2];
        p[i] = make_float4(-2.0f * x, -2.0f * y, -2.0f * z,
                           fmaf(x, x, fmaf(y, y, z * z)));
    }
}

// grid = (128, SPLIT, 2). Each block: one batch, 512 owner points (2/thread),
// sweeps CH swept points. Q address is wave-uniform (batch from blockIdx only)
// -> scalar loads; inner loop pure VALU: 12 fma + 2 min3 per 2 swept points.
__global__ __launch_bounds__(BLK)
void cham_min_kernel(const float* __restrict__ xyz1,
                     const float* __restrict__ xyz2,
                     const float4* __restrict__ q1s,  // scaled pack of cloud1
                     const float4* __restrict__ q2s,  // scaled pack of cloud2
                     float* __restrict__ part) {      // [2][SPLIT][BN]
    const int bpb = (N_ / 2) / BLK;                   // 16 blocks per batch
    const int b   = blockIdx.x / bpb;
    const int r   = (blockIdx.x % bpb) * BLK + threadIdx.x;
    const int dir = blockIdx.z;

    const float*  own = (dir == 0) ? xyz1 : xyz2;
    const float4* q   = ((dir == 0) ? q2s : q1s)
                        + (size_t)b * M_ + (size_t)blockIdx.y * CH;

    const int i0 = b * N_ + r;
    const int i1 = i0 + N_ / 2;

    const float A0x = own[3 * i0], A0y = own[3 * i0 + 1], A0z = own[3 * i0 + 2];
    const float A1x = own[3 * i1], A1y = own[3 * i1 + 1], A1z = own[3 * i1 + 2];

    float m0 = 3.0e38f, m1 = 3.0e38f;

#pragma unroll 8
    for (int j = 0; j < CH; j += 2) {
        float4 q0 = q[j];
        float4 q1 = q[j + 1];
        float d00 = fmaf(A0x, q0.x, fmaf(A0y, q0.y, fmaf(A0z, q0.z, q0.w)));
        float d01 = fmaf(A0x, q1.x, fmaf(A0y, q1.y, fmaf(A0z, q1.z, q1.w)));
        float d10 = fmaf(A1x, q0.x, fmaf(A1y, q0.y, fmaf(A1z, q0.z, q0.w)));
        float d11 = fmaf(A1x, q1.x, fmaf(A1y, q1.y, fmaf(A1z, q1.z, q1.w)));
        m0 = fminf(m0, fminf(d00, d01));   // -> v_min3_f32 candidate
        m1 = fminf(m1, fminf(d10, d11));
    }

    float* p = part + (size_t)dir * SPLIT * BN + (size_t)blockIdx.y * BN;
    p[i0] = m0;
    p[i1] = m1;
}

// One launch for both directions: i in [0, 2*BN).
__global__ void reduce_kernel(const float* __restrict__ part,
                              const float* __restrict__ xyz1,
                              const float* __restrict__ xyz2,
                              float* __restrict__ out) {
    int i = blockIdx.x * blockDim.x + threadIdx.x;
    if (i < 2 * BN) {
        int dir = i / BN;
        int ii  = i - dir * BN;
        const float* xyz = dir ? xyz2 : xyz1;
        const float* p = part + (size_t)dir * SPLIT * BN + ii;
        float m = p[0];
#pragma unroll
        for (int s = 1; s < SPLIT; ++s)
            m = fminf(m, p[(size_t)s * BN]);
        float x = xyz[3 * ii], y = xyz[3 * ii + 1], z = xyz[3 * ii + 2];
        out[i] = m + fmaf(x, x, fmaf(y, y, z * z));
    }
}

extern "C" void kernel_launch(void* const* d_in, const int* in_sizes, int n_in,
                              void* d_out, int out_size, void* d_ws, size_t ws_size,
                              hipStream_t stream) {
    const float* xyz1 = (const float*)d_in[0];
    const float* xyz2 = (const float*)d_in[1];
    float* out = (float*)d_out;

    // ws layout: q1s (1MB) | q2s (1MB) | part (2*SPLIT*BN*4 = 4MB)
    float4* q1s = (float4*)d_ws;
    float4* q2s = q1s + BN;
    float*  part = (float*)(q2s + BN);

    pack_kernel<<<BN / BLK, BLK, 0, stream>>>(xyz1, q1s, BN);
    pack_kernel<<<BN / BLK, BLK, 0, stream>>>(xyz2, q2s, BN);

    dim3 grid(B_ * (N_ / 2 / BLK), SPLIT, 2);   // (128, 8, 2)
    cham_min_kernel<<<grid, BLK, 0, stream>>>(xyz1, xyz2, q1s, q2s, part);

    reduce_kernel<<<(2 * BN) / BLK, BLK, 0, stream>>>(part, xyz1, xyz2, out);
}

// Round 3
// 96.217 us; speedup vs baseline: 1.7315x; 1.4567x over previous
//
#include <hip/hip_runtime.h>

// Chamfer distance, B=8, N=M=8192, fp32.
// Swept points staged per-block into LDS as q' = (-2x,-2y,-2z, x^2+y^2+z^2):
//   d(i,j) - sq_i = fma(Ax,q'x, fma(Ay,q'y, fma(Az,q'z, q'w)))
// Inner loop: 12 v_fma + 2 v_min3 per (2 swept x 2 owners) = 3.5 VALU ops/pair.
// LDS reads are wave-uniform-address (broadcast, conflict-free) and issue on
// the LDS pipe in parallel with VALU. Owner sq_i added in the reduce.

#define B_    8
#define N_    8192
#define M_    8192
#define SPLIT 8
#define BLK   256
#define BN    (B_ * N_)        // 65536
#define CH    (M_ / SPLIT)     // 1024 swept points per block (16 KB LDS)
#define OPB   (BLK * 2)        // 512 owner points per block (2 per thread)
#define BPB   (N_ / OPB)       // 16 blocks per batch

// grid = (B_*BPB, SPLIT, 2) = (128, 8, 2) = 2048 blocks = 8 blocks/CU resident.
__global__ __launch_bounds__(BLK, 8)   // force VGPR<=64 so 32 waves/CU fit
void cham_min_kernel(const float* __restrict__ xyz1,
                     const float* __restrict__ xyz2,
                     float* __restrict__ part) {   // [2][SPLIT][BN]
    __shared__ float4 sq[CH];                      // 16 KB

    const int b   = blockIdx.x / BPB;
    const int r   = (blockIdx.x % BPB) * OPB + threadIdx.x;
    const int dir = blockIdx.z;

    const float* __restrict__ own  = (dir == 0) ? xyz1 : xyz2;
    const float* __restrict__ qraw = ((dir == 0) ? xyz2 : xyz1)
                                     + ((size_t)b * M_ + (size_t)blockIdx.y * CH) * 3;

    // Stage + pack swept chunk into LDS (fused pack step).
#pragma unroll
    for (int t0 = 0; t0 < CH; t0 += BLK) {
        int t = t0 + threadIdx.x;
        float x = qraw[3 * t], y = qraw[3 * t + 1], z = qraw[3 * t + 2];
        sq[t] = make_float4(-2.0f * x, -2.0f * y, -2.0f * z,
                            fmaf(x, x, fmaf(y, y, z * z)));
    }

    const int i0 = b * N_ + r;
    const int i1 = i0 + BLK;            // +256: stores stay coalesced
    const float A0x = own[3 * i0], A0y = own[3 * i0 + 1], A0z = own[3 * i0 + 2];
    const float A1x = own[3 * i1], A1y = own[3 * i1 + 1], A1z = own[3 * i1 + 2];

    __syncthreads();

    float m0 = 3.0e38f, m1 = 3.0e38f;

#pragma unroll 4
    for (int j = 0; j < CH; j += 2) {
        float4 q0 = sq[j];
        float4 q1 = sq[j + 1];
        float d00 = fmaf(A0x, q0.x, fmaf(A0y, q0.y, fmaf(A0z, q0.z, q0.w)));
        float d01 = fmaf(A0x, q1.x, fmaf(A0y, q1.y, fmaf(A0z, q1.z, q1.w)));
        float d10 = fmaf(A1x, q0.x, fmaf(A1y, q0.y, fmaf(A1z, q0.z, q0.w)));
        float d11 = fmaf(A1x, q1.x, fmaf(A1y, q1.y, fmaf(A1z, q1.z, q1.w)));
        m0 = fminf(m0, fminf(d00, d01));   // -> v_min3_f32
        m1 = fminf(m1, fminf(d10, d11));
    }

    float* p = part + ((size_t)dir * SPLIT + blockIdx.y) * BN;
    p[i0] = m0;
    p[i1] = m1;
}

// min over SPLIT partials + add owner sq. One launch, i in [0, 2*BN).
__global__ void reduce_kernel(const float* __restrict__ part,
                              const float* __restrict__ xyz1,
                              const float* __restrict__ xyz2,
                              float* __restrict__ out) {
    int i = blockIdx.x * blockDim.x + threadIdx.x;
    if (i < 2 * BN) {
        int dir = i / BN;
        int ii  = i - dir * BN;
        const float* xyz = dir ? xyz2 : xyz1;
        const float* p = part + (size_t)dir * SPLIT * BN + ii;
        float m = p[0];
#pragma unroll
        for (int s = 1; s < SPLIT; ++s)
            m = fminf(m, p[(size_t)s * BN]);
        float x = xyz[3 * ii], y = xyz[3 * ii + 1], z = xyz[3 * ii + 2];
        out[i] = m + fmaf(x, x, fmaf(y, y, z * z));
    }
}

extern "C" void kernel_launch(void* const* d_in, const int* in_sizes, int n_in,
                              void* d_out, int out_size, void* d_ws, size_t ws_size,
                              hipStream_t stream) {
    const float* xyz1 = (const float*)d_in[0];
    const float* xyz2 = (const float*)d_in[1];
    float* out = (float*)d_out;

    float* part = (float*)d_ws;   // 2*SPLIT*BN*4 = 4 MB

    dim3 grid(B_ * BPB, SPLIT, 2);   // (128, 8, 2)
    cham_min_kernel<<<grid, BLK, 0, stream>>>(xyz1, xyz2, part);

    reduce_kernel<<<(2 * BN) / BLK, BLK, 0, stream>>>(part, xyz1, xyz2, out);
}

// Round 4
// 93.649 us; speedup vs baseline: 1.7789x; 1.0274x over previous
//
#include <hip/hip_runtime.h>

// Chamfer distance, B=8, N=M=8192, fp32.
// Swept points staged per-block into LDS as q' = (-2x,-2y,-2z, x^2+y^2+z^2):
//   d(i,j) - sq_i = fma(Ax,q'x, fma(Ay,q'y, fma(Az,q'z, q'w)))
// U=8 owners per thread amortizes each LDS broadcast read over 8 owners
// (LDS pipe was the round-3 bottleneck). Per-direction mins combined across
// SPLIT j-chunks via order-preserving uint atomicMin; sq_i added at decode.

#define B_    8
#define N_    8192
#define M_    8192
#define SPLIT 16
#define BLK   256
#define U     8                 // owners per thread
#define BN    (B_ * N_)         // 65536
#define CH    (M_ / SPLIT)      // 512 swept points per block (8 KB LDS)
#define OPB   (BLK * U)         // 2048 owner points per block
#define BPB   (N_ / OPB)        // 4 blocks per batch-stripe

__device__ __forceinline__ unsigned key_of(float f) {
    unsigned u = __float_as_uint(f);
    return (u & 0x80000000u) ? ~u : (u | 0x80000000u);
}
__device__ __forceinline__ float val_of(unsigned k) {
    return __uint_as_float((k & 0x80000000u) ? (k & 0x7FFFFFFFu) : ~k);
}

__global__ void init_kernel(unsigned* __restrict__ enc) {
    int i = blockIdx.x * blockDim.x + threadIdx.x;
    if (i < 2 * BN) enc[i] = 0xFFFFFFFFu;
}

// grid = (B_*BPB, SPLIT, 2) = (32, 16, 2) = 1024 blocks = 4 blocks/CU.
__global__ __launch_bounds__(BLK, 4)
void cham_min_kernel(const float* __restrict__ xyz1,
                     const float* __restrict__ xyz2,
                     unsigned* __restrict__ enc) {    // [2][BN] encoded mins
    __shared__ float4 sq[CH];                          // 8 KB

    const int b   = blockIdx.x / BPB;
    const int str = blockIdx.x % BPB;
    const int dir = blockIdx.z;

    const float* __restrict__ own  = (dir == 0) ? xyz1 : xyz2;
    const float* __restrict__ qraw = ((dir == 0) ? xyz2 : xyz1)
                                     + ((size_t)b * M_ + (size_t)blockIdx.y * CH) * 3;

    // Stage + pack swept chunk into LDS.
#pragma unroll
    for (int t0 = 0; t0 < CH; t0 += BLK) {
        int t = t0 + threadIdx.x;
        float x = qraw[3 * t], y = qraw[3 * t + 1], z = qraw[3 * t + 2];
        sq[t] = make_float4(-2.0f * x, -2.0f * y, -2.0f * z,
                            fmaf(x, x, fmaf(y, y, z * z)));
    }

    const int base = b * N_ + str * OPB + threadIdx.x;   // owner 0 of this thread
    float Ax[U], Ay[U], Az[U], m[U];
#pragma unroll
    for (int k = 0; k < U; ++k) {
        int i = base + k * BLK;
        Ax[k] = own[3 * i]; Ay[k] = own[3 * i + 1]; Az[k] = own[3 * i + 2];
        m[k] = 3.0e38f;
    }

    __syncthreads();

#pragma unroll 4
    for (int j = 0; j < CH; j += 2) {
        float4 q0 = sq[j];
        float4 q1 = sq[j + 1];
#pragma unroll
        for (int k = 0; k < U; ++k) {
            float d0 = fmaf(Ax[k], q0.x, fmaf(Ay[k], q0.y, fmaf(Az[k], q0.z, q0.w)));
            float d1 = fmaf(Ax[k], q1.x, fmaf(Ay[k], q1.y, fmaf(Az[k], q1.z, q1.w)));
            m[k] = fminf(m[k], fminf(d0, d1));   // -> v_min3_f32
        }
    }

    unsigned* e = enc + (size_t)dir * BN;
#pragma unroll
    for (int k = 0; k < U; ++k)
        atomicMin(&e[base + k * BLK], key_of(m[k]));
}

// decode + add owner squared norm. i in [0, 2*BN).
__global__ void decode_kernel(const unsigned* __restrict__ enc,
                              const float* __restrict__ xyz1,
                              const float* __restrict__ xyz2,
                              float* __restrict__ out) {
    int i = blockIdx.x * blockDim.x + threadIdx.x;
    if (i < 2 * BN) {
        int dir = i / BN;
        int ii  = i - dir * BN;
        const float* xyz = dir ? xyz2 : xyz1;
        float x = xyz[3 * ii], y = xyz[3 * ii + 1], z = xyz[3 * ii + 2];
        out[i] = val_of(enc[i]) + fmaf(x, x, fmaf(y, y, z * z));
    }
}

extern "C" void kernel_launch(void* const* d_in, const int* in_sizes, int n_in,
                              void* d_out, int out_size, void* d_ws, size_t ws_size,
                              hipStream_t stream) {
    const float* xyz1 = (const float*)d_in[0];
    const float* xyz2 = (const float*)d_in[1];
    float* out = (float*)d_out;

    unsigned* enc = (unsigned*)d_ws;   // 2*BN*4 = 512 KB

    init_kernel<<<(2 * BN) / BLK, BLK, 0, stream>>>(enc);

    dim3 grid(B_ * BPB, SPLIT, 2);     // (32, 16, 2)
    cham_min_kernel<<<grid, BLK, 0, stream>>>(xyz1, xyz2, enc);

    decode_kernel<<<(2 * BN) / BLK, BLK, 0, stream>>>(enc, xyz1, xyz2, out);
}